// Round 7
// baseline (420.279 us; speedup 1.0000x reference)
//
#include <hip/hip_runtime.h>
#include <hip/hip_bf16.h>
#include <stdint.h>

#define TT 8192   // tokens
#define HH 1024   // hidden
#define II 2048   // intermediate
#define EE 8      // experts
#define TOPK 2

typedef __bf16 bf16x8 __attribute__((ext_vector_type(8)));
typedef float f32x4 __attribute__((ext_vector_type(4)));

__device__ __forceinline__ unsigned short f2bf(float f) {
  union { float f; unsigned int u; } c; c.f = f;
  unsigned int u = c.u;
  u += 0x7FFFu + ((u >> 16) & 1u);   // RNE
  return (unsigned short)(u >> 16);
}

__device__ __forceinline__ void gload_lds16(const void* g, void* l) {
  __builtin_amdgcn_global_load_lds((const __attribute__((address_space(1))) void*)g,
                                   (__attribute__((address_space(3))) void*)l, 16, 0, 0);
}

// -------- transpose + convert: src [E][R][C] fp32 -> dst [E][C][R] bf16 --------
__global__ __launch_bounds__(256) void k_transpose_cvt(const float* __restrict__ src,
                                                       unsigned short* __restrict__ dst,
                                                       int R, int C) {
  __shared__ float tile[64][65];
  const float* s = src + (size_t)blockIdx.z * R * C;
  unsigned short* d = dst + (size_t)blockIdx.z * R * C;
  int r0 = blockIdx.y * 64, c0 = blockIdx.x * 64;
  int tx = threadIdx.x & 15;
  int ty = threadIdx.x >> 4;
#pragma unroll
  for (int i = 0; i < 4; ++i) {
    int rr = i * 16 + ty;
    float4 v = *reinterpret_cast<const float4*>(&s[(size_t)(r0 + rr) * C + c0 + tx * 4]);
    tile[rr][tx * 4 + 0] = v.x; tile[rr][tx * 4 + 1] = v.y;
    tile[rr][tx * 4 + 2] = v.z; tile[rr][tx * 4 + 3] = v.w;
  }
  __syncthreads();
#pragma unroll
  for (int i = 0; i < 4; ++i) {
    int cc = i * 16 + ty;
    ushort4 o;
    o.x = f2bf(tile[tx * 4 + 0][cc]);
    o.y = f2bf(tile[tx * 4 + 1][cc]);
    o.z = f2bf(tile[tx * 4 + 2][cc]);
    o.w = f2bf(tile[tx * 4 + 3][cc]);
    *reinterpret_cast<ushort4*>(&d[(size_t)(c0 + cc) * R + r0 + tx * 4]) = o;
  }
}

// ---- transpose Wg/Wu [E][H][I] fp32 -> interleaved WguT [E][2I][H] bf16 ----
// stored row s: gate col j=(s>>5)*16+(s&15) if (s>>4)&1==0, else up col j.
__global__ __launch_bounds__(256) void k_transpose_wgu(const float* __restrict__ src,
                                                       unsigned short* __restrict__ dst,
                                                       int mat) {
  __shared__ float tile[64][65];
  const float* s = src + (size_t)blockIdx.z * HH * II;
  unsigned short* d = dst + (size_t)blockIdx.z * 2 * II * HH;
  int r0 = blockIdx.y * 64, c0 = blockIdx.x * 64;   // r0 over H, c0 over I
  int tx = threadIdx.x & 15;
  int ty = threadIdx.x >> 4;
#pragma unroll
  for (int i = 0; i < 4; ++i) {
    int rr = i * 16 + ty;
    float4 v = *reinterpret_cast<const float4*>(&s[(size_t)(r0 + rr) * II + c0 + tx * 4]);
    tile[rr][tx * 4 + 0] = v.x; tile[rr][tx * 4 + 1] = v.y;
    tile[rr][tx * 4 + 2] = v.z; tile[rr][tx * 4 + 3] = v.w;
  }
  __syncthreads();
#pragma unroll
  for (int i = 0; i < 4; ++i) {
    int cc = i * 16 + ty;
    int srow = c0 * 2 + ((cc >> 4) << 5) + mat * 16 + (cc & 15);
    ushort4 o;
    o.x = f2bf(tile[tx * 4 + 0][cc]);
    o.y = f2bf(tile[tx * 4 + 1][cc]);
    o.z = f2bf(tile[tx * 4 + 2][cc]);
    o.w = f2bf(tile[tx * 4 + 3][cc]);
    *reinterpret_cast<ushort4*>(&d[(size_t)srow * HH + r0 + tx * 4]) = o;
  }
}

// ---------------- router: logits, top-2, sigmoid-renorm, expert lists ----------------
__global__ __launch_bounds__(256) void k_router(const float* __restrict__ x,
                                                const float* __restrict__ Wr,
                                                const float* __restrict__ br,
                                                unsigned short* __restrict__ xb,
                                                int* __restrict__ tlist,
                                                float* __restrict__ glist,
                                                int* __restrict__ counts) {
  __shared__ float wrt[8][1024];
  __shared__ int lcount[8];
  __shared__ int lbase[8];
  __shared__ short ent_e[128];
  __shared__ short ent_slot[128];
  __shared__ float ent_g[128];
  int tid = threadIdx.x;
  for (int i = tid; i < 8192; i += 256) {
    wrt[i & 7][i >> 3] = Wr[i];
  }
  if (tid < 8) lcount[tid] = 0;
  __syncthreads();
  int w = tid >> 6, l = tid & 63;
  int t0 = blockIdx.x * 64;
  for (int it = 0; it < 16; ++it) {
    int t = t0 + w * 16 + it;
    const float4* xr = reinterpret_cast<const float4*>(x + (size_t)t * HH);
    float acc[8] = {0.f, 0.f, 0.f, 0.f, 0.f, 0.f, 0.f, 0.f};
#pragma unroll
    for (int j = 0; j < 4; ++j) {
      float4 xv = xr[j * 64 + l];
      int hbase = (j * 64 + l) * 4;
      ushort4 o;
      o.x = f2bf(xv.x); o.y = f2bf(xv.y); o.z = f2bf(xv.z); o.w = f2bf(xv.w);
      *reinterpret_cast<ushort4*>(xb + (size_t)t * HH + hbase) = o;
#pragma unroll
      for (int e = 0; e < 8; ++e) {
        float4 wv = *reinterpret_cast<const float4*>(&wrt[e][hbase]);
        acc[e] += xv.x * wv.x + xv.y * wv.y + xv.z * wv.z + xv.w * wv.w;
      }
    }
#pragma unroll
    for (int e = 0; e < 8; ++e)
#pragma unroll
      for (int off = 32; off > 0; off >>= 1) acc[e] += __shfl_xor(acc[e], off, 64);
    if (l == 0) {
      float lg[8];
#pragma unroll
      for (int e = 0; e < 8; ++e) lg[e] = acc[e] + br[e];
      int i0 = 0;
#pragma unroll
      for (int e = 1; e < 8; ++e) if (lg[e] > lg[i0]) i0 = e;
      int i1 = (i0 == 0) ? 1 : 0;
#pragma unroll
      for (int e = 0; e < 8; ++e) if (e != i0 && lg[e] > lg[i1]) i1 = e;
      float g0 = 1.f / (1.f + expf(-lg[i0]));
      float g1 = 1.f / (1.f + expf(-lg[i1]));
      float inv = 1.f / (g0 + g1 + 1e-10f);
      int idx = (w * 16 + it) * 2;
      int s0 = atomicAdd(&lcount[i0], 1);
      ent_e[idx] = (short)i0; ent_slot[idx] = (short)s0; ent_g[idx] = g0 * inv;
      int s1 = atomicAdd(&lcount[i1], 1);
      ent_e[idx + 1] = (short)i1; ent_slot[idx + 1] = (short)s1; ent_g[idx + 1] = g1 * inv;
    }
  }
  __syncthreads();
  if (tid < 8) lbase[tid] = atomicAdd(&counts[tid], lcount[tid]);
  __syncthreads();
  if (tid < 128) {
    int e = ent_e[tid];
    int slot = lbase[e] + ent_slot[tid];
    int t = t0 + (tid >> 1);
    tlist[e * TT + slot] = t;
    glist[e * TT + slot] = ent_g[tid];
  }
}

__global__ void k_offsets(const int* __restrict__ counts, int* __restrict__ offs) {
  if (threadIdx.x == 0) {
    int s = 0;
    for (int e = 0; e < EE; ++e) { offs[e] = s; s += counts[e]; }
  }
}

// ============ GEMM1: 256x256 8-phase schedule (m201 template port) ============
// BK=64, 8 waves (2M halves x 4N), per-wave out 128x64. LDS: 2 dbuf x
// {A[2 half][128x64], B[2 half][128x64]} = 128 KiB, 1 block/CU. Per K-tile:
// 4 phases {ds_read A-quadrant (+B all on q0) | stage 1 half-tile | barrier |
// lgkmcnt(0) | setprio(1) 16 MFMA setprio(0) | barrier}. Counted vmcnt(4) at
// phases 4/8 only (vmcnt(0) final iter). Half-tile staging staggered so every
// LDS write lands in a buffer whose reads finished before a prior barrier:
//   p0: d1.A0(khi)  p1: d1.A1(khi), d0.B0(klo+2)  p2: d0.B1(klo+2)
//   p3: vmcnt(4)    p4: d0.A0(klo+2)  p5: d0.A1(klo+2)
//   p6: d1.B0(khi+2) p7: d1.B1(khi+2), vmcnt(4)
// In-flight ledger: steady state 4-12 loads; drain targets verified per iter.
#define READB(BP) do { _Pragma("unroll") \
  for (int n = 0; n < 4; ++n) { \
    bfr[2*n]   = *(const bf16x8*)((BP) + ((bbase + n*2048 + 0 ) ^ swz)); \
    bfr[2*n+1] = *(const bf16x8*)((BP) + ((bbase + n*2048 + 64) ^ swz)); } } while(0)

#define PHASE(AP, Q, STAGE_CODE, TAIL_CODE) do { \
  bf16x8 af0 = *(const bf16x8*)((AP) + ((abase + (2*(Q))*2048 + 0 ) ^ swz)); \
  bf16x8 af1 = *(const bf16x8*)((AP) + ((abase + (2*(Q))*2048 + 64) ^ swz)); \
  bf16x8 af2 = *(const bf16x8*)((AP) + ((abase + (2*(Q)+1)*2048 + 0 ) ^ swz)); \
  bf16x8 af3 = *(const bf16x8*)((AP) + ((abase + (2*(Q)+1)*2048 + 64) ^ swz)); \
  STAGE_CODE; \
  __builtin_amdgcn_sched_barrier(0); \
  __builtin_amdgcn_s_barrier(); \
  asm volatile("s_waitcnt lgkmcnt(0)" ::: "memory"); \
  __builtin_amdgcn_sched_barrier(0); \
  __builtin_amdgcn_s_setprio(1); \
  _Pragma("unroll") \
  for (int n = 0; n < 4; ++n) { \
    acc[2*(Q)][n]   = __builtin_amdgcn_mfma_f32_16x16x32_bf16(af0, bfr[2*n],   acc[2*(Q)][n],   0,0,0); \
    acc[2*(Q)][n]   = __builtin_amdgcn_mfma_f32_16x16x32_bf16(af1, bfr[2*n+1], acc[2*(Q)][n],   0,0,0); \
    acc[2*(Q)+1][n] = __builtin_amdgcn_mfma_f32_16x16x32_bf16(af2, bfr[2*n],   acc[2*(Q)+1][n], 0,0,0); \
    acc[2*(Q)+1][n] = __builtin_amdgcn_mfma_f32_16x16x32_bf16(af3, bfr[2*n+1], acc[2*(Q)+1][n], 0,0,0); \
  } \
  __builtin_amdgcn_s_setprio(0); \
  TAIL_CODE; \
  __builtin_amdgcn_sched_barrier(0); \
  __builtin_amdgcn_s_barrier(); \
  __builtin_amdgcn_sched_barrier(0); \
} while(0)

#define VM4() asm volatile("s_waitcnt vmcnt(4)" ::: "memory")
#define VM0() asm volatile("s_waitcnt vmcnt(0)" ::: "memory")

__global__ __launch_bounds__(512, 1) void k_gemm1(
    const unsigned short* __restrict__ xb,
    const unsigned short* __restrict__ WguT,
    const int* __restrict__ tlist, const float* __restrict__ glist,
    const int* __restrict__ counts, const int* __restrict__ offs,
    unsigned short* __restrict__ hbuf) {
  __shared__ unsigned short lsA[2][2][128 * 64];   // [dbuf][half] 64 KB
  __shared__ unsigned short lsB[2][2][128 * 64];   // 64 KB
  __shared__ int s_tok[256];
  __shared__ float s_gate[256];

  const int e = blockIdx.z;
  const int n_e = counts[e];
  const int row0 = blockIdx.y * 256;
  if (row0 >= n_e) return;
  const int n0 = blockIdx.x * 256;   // stored-row base in WguT
  const int tid = threadIdx.x;

  if (tid < 256) {
    int r = row0 + tid;
    int tok = 0; float gt = 0.f;
    if (r < n_e) { tok = tlist[e * TT + r]; gt = glist[e * TT + r]; }
    s_tok[tid] = tok; s_gate[tid] = gt;
  }
  __syncthreads();

  // staging sources: row = tid>>3 within 64-row group, pre-swizzled 16B chunk
  const int sr = tid >> 3;
  const int sc = ((tid & 7) ^ (sr & 7)) * 8;
  const unsigned short* sA[4];
  const unsigned short* sB[4];
#pragma unroll
  for (int h = 0; h < 2; ++h)
#pragma unroll
    for (int j = 0; j < 2; ++j) {
      sA[h * 2 + j] = xb + (size_t)s_tok[h * 128 + j * 64 + sr] * HH + sc;
      sB[h * 2 + j] = WguT + ((size_t)e * 2 * II + n0 + h * 128 + j * 64 + sr) * HH + sc;
    }

  auto SA = [&](int d, int h, int kt) {
    gload_lds16(sA[h * 2 + 0] + kt * 64, (char*)&lsA[d][h][0] + tid * 16);
    gload_lds16(sA[h * 2 + 1] + kt * 64, (char*)&lsA[d][h][0] + 8192 + tid * 16);
  };
  auto SB = [&](int d, int h, int kt) {
    gload_lds16(sB[h * 2 + 0] + kt * 64, (char*)&lsB[d][h][0] + tid * 16);
    gload_lds16(sB[h * 2 + 1] + kt * 64, (char*)&lsB[d][h][0] + 8192 + tid * 16);
  };

  const int l = tid & 63;
  const int w = tid >> 6;
  const int hA = w >> 2;            // wave's A half (M 0-127 / 128-255)
  const int wcl = (w & 3) * 64;     // stored-col base within 256
  const int cb = wcl & 127;         // col base within B half
  const int lrow = l & 15;
  const int lk = l >> 4;
  const int swz = (l & 7) << 4;
  const int abase = lrow * 128 + lk * 16;
  const int bbase = (cb + lrow) * 128 + lk * 16;
  const char* a0 = (const char*)&lsA[0][hA][0];
  const char* a1 = (const char*)&lsA[1][hA][0];
  const char* b0 = (const char*)&lsB[0][wcl >> 7][0];
  const char* b1 = (const char*)&lsB[1][wcl >> 7][0];

  f32x4 zero = {0.f, 0.f, 0.f, 0.f};
  f32x4 acc[8][4];
#pragma unroll
  for (int m = 0; m < 8; ++m)
#pragma unroll
    for (int n = 0; n < 4; ++n) acc[m][n] = zero;

  // prologue: tile0 (d0) full + tile1 (d1) B halves; leftover after vmcnt = d1.B (4)
  SA(0, 0, 0); SA(0, 1, 0); SB(0, 0, 0); SB(0, 1, 0);
  SB(1, 0, 1); SB(1, 1, 1);
  VM4();
  __builtin_amdgcn_sched_barrier(0);
  __builtin_amdgcn_s_barrier();
  __builtin_amdgcn_sched_barrier(0);

  bf16x8 bfr[8];
#pragma unroll 1
  for (int it = 0; it < HH / 128; ++it) {
    const bool pf = (it < HH / 128 - 1);
    const int klo = 2 * it, khi = 2 * it + 1;

    READB(b0);
    PHASE(a0, 0, { SA(1, 0, khi); }, {});
    PHASE(a0, 1, { SA(1, 1, khi); __builtin_amdgcn_sched_barrier(0);
                   if (pf) SB(0, 0, klo + 2); }, {});
    PHASE(a0, 2, { if (pf) SB(0, 1, klo + 2); }, {});
    PHASE(a0, 3, {}, { if (pf) VM4(); else VM0(); });
    READB(b1);
    PHASE(a1, 0, { if (pf) SA(0, 0, klo + 2); }, {});
    PHASE(a1, 1, { if (pf) SA(0, 1, klo + 2); }, {});
    PHASE(a1, 2, { if (pf) SB(1, 0, khi + 2); }, {});
    PHASE(a1, 3, { if (pf) SB(1, 1, khi + 2); }, { if (pf) VM4(); else VM0(); });
  }

  // epilogue: silu-combine interleaved gate/up pairs, write hbuf
  const int obase = offs[e];
#pragma unroll
  for (int m = 0; m < 8; ++m)
#pragma unroll
    for (int n = 0; n < 4; n += 2)   // n = gate frag, n+1 = up frag (same cols)
#pragma unroll
      for (int r = 0; r < 4; ++r) {
        int rl = hA * 128 + m * 16 + lk * 4 + r;
        if (row0 + rl < n_e) {
          float gv = acc[m][n][r];
          float uv = acc[m][n + 1][r];
          float val = gv / (1.f + __expf(-gv)) * uv * s_gate[rl];
          int L = ((n0 + wcl) >> 1) + (n >> 1) * 16 + lrow;   // logical II col
          hbuf[(size_t)(obase + row0 + rl) * II + L] = f2bf(val);
        }
      }
}

// ---------------- GEMM2: out += h @ Wd (R6-proven 2-barrier, atomic scatter) ----
__global__ __launch_bounds__(256, 4) void k_gemm2(
    const unsigned short* __restrict__ hbuf,
    const unsigned short* __restrict__ WdT,   // [E][H][I] (k=I contiguous)
    const int* __restrict__ tlist,
    const int* __restrict__ counts, const int* __restrict__ offs,
    float* __restrict__ out) {
  __shared__ unsigned short lsA[128 * 64];
  __shared__ unsigned short lsB[128 * 64];
  __shared__ int s_tok[128];

  const int e = blockIdx.z;
  const int n_e = counts[e];
  const int row0 = blockIdx.y * 128;
  if (row0 >= n_e) return;
  const int n0 = blockIdx.x * 128;   // H columns
  const int tid = threadIdx.x;
  const int obase = offs[e];

  if (tid < 128) {
    int r = row0 + tid;
    s_tok[tid] = (r < n_e) ? tlist[e * TT + r] : 0;
  }
  __syncthreads();

  const int scol = (tid & 7) ^ ((tid >> 3) & 7);
  const unsigned short* srcA[4];
  const unsigned short* srcB[4];
#pragma unroll
  for (int i = 0; i < 4; ++i) {
    int row = i * 32 + (tid >> 3);
    int ar = obase + row0 + row;
    if (ar > TT * TOPK - 1) ar = TT * TOPK - 1;   // clamp pad rows inside hbuf
    srcA[i] = hbuf + (size_t)ar * II + scol * 8;
    srcB[i] = WdT + ((size_t)e * HH + n0 + row) * II + scol * 8;
  }

  f32x4 zero = {0.f, 0.f, 0.f, 0.f};
  f32x4 acc[4][4];
#pragma unroll
  for (int m = 0; m < 4; ++m)
#pragma unroll
    for (int n = 0; n < 4; ++n) acc[m][n] = zero;

  const int l = tid & 63;
  const int w = tid >> 6;
  const int wr = (w >> 1) * 64;
  const int wc = (w & 1) * 64;
  const int lrow = l & 15;
  const int lk = l >> 4;
  const int swz = (l & 7) << 4;
  const int aoff0 = (wr + lrow) * 128 + lk * 16;
  const int boff0 = (wc + lrow) * 128 + lk * 16;
  const char* lcA = (const char*)lsA;
  const char* lcB = (const char*)lsB;

  for (int kt = 0; kt < II / 64; ++kt) {
#pragma unroll
    for (int i = 0; i < 4; ++i) {
      gload_lds16(srcA[i] + kt * 64, (char*)lsA + i * 4096 + tid * 16);
      gload_lds16(srcB[i] + kt * 64, (char*)lsB + i * 4096 + tid * 16);
    }
    __syncthreads();
#pragma unroll
    for (int kk = 0; kk < 2; ++kk) {
      bf16x8 af[4], bf[4];
#pragma unroll
      for (int m = 0; m < 4; ++m)
        af[m] = *(const bf16x8*)(lcA + ((aoff0 + m * 2048 + kk * 64) ^ swz));
#pragma unroll
      for (int n = 0; n < 4; ++n)
        bf[n] = *(const bf16x8*)(lcB + ((boff0 + n * 2048 + kk * 64) ^ swz));
#pragma unroll
      for (int m = 0; m < 4; ++m)
#pragma unroll
        for (int n = 0; n < 4; ++n)
          acc[m][n] = __builtin_amdgcn_mfma_f32_16x16x32_bf16(af[m], bf[n], acc[m][n], 0, 0, 0);
    }
    __syncthreads();
  }

#pragma unroll
  for (int m = 0; m < 4; ++m)
#pragma unroll
    for (int n = 0; n < 4; ++n)
#pragma unroll
      for (int r = 0; r < 4; ++r) {
        int rl = wr + m * 16 + lk * 4 + r;
        if (row0 + rl < n_e) {
          int t = s_tok[rl];
          unsafeAtomicAdd(&out[(size_t)t * HH + n0 + wc + n * 16 + lrow], acc[m][n][r]);
        }
      }
}

extern "C" void kernel_launch(void* const* d_in, const int* in_sizes, int n_in,
                              void* d_out, int out_size, void* d_ws, size_t ws_size,
                              hipStream_t stream) {
  const float* x  = (const float*)d_in[0];
  const float* Wr = (const float*)d_in[1];
  const float* br = (const float*)d_in[2];
  const float* Wg = (const float*)d_in[3];
  const float* Wu = (const float*)d_in[4];
  const float* Wd = (const float*)d_in[5];
  float* out = (float*)d_out;

  char* ws = (char*)d_ws;
  size_t off = 0;
  auto alloc = [&](size_t bytes) {
    char* p = ws + off;
    off += (bytes + 255) & ~(size_t)255;
    return p;
  };
  unsigned short* xb   = (unsigned short*)alloc((size_t)TT * HH * 2);            // 16 MB
  unsigned short* WguT = (unsigned short*)alloc((size_t)EE * 2 * II * HH * 2);   // 64 MB
  unsigned short* WdT  = (unsigned short*)alloc((size_t)EE * HH * II * 2);       // 32 MB
  unsigned short* hbuf = (unsigned short*)alloc((size_t)TT * TOPK * II * 2);     // 64 MB
  int*   tlist  = (int*)alloc((size_t)EE * TT * 4);
  float* glist  = (float*)alloc((size_t)EE * TT * 4);
  int*   counts = (int*)alloc(128);
  int*   offs   = (int*)alloc(128);

  hipMemsetAsync(counts, 0, 128, stream);
  hipMemsetAsync(d_out, 0, (size_t)TT * HH * 4, stream);

  dim3 tgu(II / 64, HH / 64, EE);   // Wg/Wu -> interleaved WguT
  k_transpose_wgu<<<tgu, 256, 0, stream>>>(Wg, WguT, 0);
  k_transpose_wgu<<<tgu, 256, 0, stream>>>(Wu, WguT, 1);
  dim3 tg2(HH / 64, II / 64, EE);   // Wd: [I][H] -> [H][I]
  k_transpose_cvt<<<tg2, 256, 0, stream>>>(Wd, WdT, II, HH);

  k_router<<<TT / 64, 256, 0, stream>>>(x, Wr, br, xb, tlist, glist, counts);
  k_offsets<<<1, 64, 0, stream>>>(counts, offs);

  dim3 g1(2 * II / 256, TT / 256, EE);   // 16 x 32 x 8, early-exit on empty M-tiles
  k_gemm1<<<g1, 512, 0, stream>>>(xb, WguT, tlist, glist, counts, offs, hbuf);
  dim3 g2(HH / 128, TT / 128, EE);
  k_gemm2<<<g2, 256, 0, stream>>>(hbuf, WdT, tlist, counts, offs, out);

  (void)in_sizes; (void)n_in; (void)out_size; (void)ws_size;
}

// Round 8
// 381.156 us; speedup vs baseline: 1.1026x; 1.1026x over previous
//
#include <hip/hip_runtime.h>
#include <hip/hip_bf16.h>
#include <stdint.h>

#define TT 8192   // tokens
#define HH 1024   // hidden
#define II 2048   // intermediate
#define EE 8      // experts
#define TOPK 2

typedef __bf16 bf16x8 __attribute__((ext_vector_type(8)));
typedef float f32x4 __attribute__((ext_vector_type(4)));
typedef unsigned short us8 __attribute__((ext_vector_type(8)));

__device__ __forceinline__ unsigned short f2bf(float f) {
  union { float f; unsigned int u; } c; c.f = f;
  unsigned int u = c.u;
  u += 0x7FFFu + ((u >> 16) & 1u);   // RNE
  return (unsigned short)(u >> 16);
}

__device__ __forceinline__ void gload_lds16(const void* g, void* l) {
  __builtin_amdgcn_global_load_lds((const __attribute__((address_space(1))) void*)g,
                                   (__attribute__((address_space(3))) void*)l, 16, 0, 0);
}

// ==== fused transpose+convert: Wg,Wu -> interleaved WguT; Wd -> WdT ====
// blockIdx.y = job (0=Wg,1=Wu,2=Wd), blockIdx.z = expert, blockIdx.x = tile.
// WguT stored row s: gate col j=(s>>5)*16+(s&15) if (s>>4)&1==0, else up col j.
// 16B vector stores; LDS read bank = (8*ch + j + cc) % 32 -> 2-way (free).
__global__ __launch_bounds__(256) void k_transpose_all(
    const float* __restrict__ Wg, const float* __restrict__ Wu,
    const float* __restrict__ Wd,
    unsigned short* __restrict__ WguT, unsigned short* __restrict__ WdT) {
  __shared__ float tile[64][65];
  const int job = blockIdx.y;
  const int e = blockIdx.z;
  const int x = blockIdx.x;
  const float* src; int C, r0, c0;
  if (job < 2) {   // Wg/Wu: [H][I], tiles: 32 over C=I, 16 over R=H
    src = (job ? Wu : Wg) + (size_t)e * HH * II;
    C = II; c0 = (x & 31) * 64; r0 = (x >> 5) * 64;
  } else {         // Wd: [I][H], tiles: 16 over C=H, 32 over R=I
    src = Wd + (size_t)e * II * HH;
    C = HH; c0 = (x & 15) * 64; r0 = (x >> 4) * 64;
  }
  const int tid = threadIdx.x;
  const int tx = tid & 15, ty = tid >> 4;
#pragma unroll
  for (int i = 0; i < 4; ++i) {
    int rr = i * 16 + ty;
    float4 v = *reinterpret_cast<const float4*>(&src[(size_t)(r0 + rr) * C + c0 + tx * 4]);
    tile[rr][tx * 4 + 0] = v.x; tile[rr][tx * 4 + 1] = v.y;
    tile[rr][tx * 4 + 2] = v.z; tile[rr][tx * 4 + 3] = v.w;
  }
  __syncthreads();
#pragma unroll
  for (int i = 0; i < 2; ++i) {
    int idx = i * 256 + tid;
    int cc = idx >> 3, ch = idx & 7;   // out-row cc, 16B chunk ch
    us8 o;
#pragma unroll
    for (int j = 0; j < 8; ++j) o[j] = f2bf(tile[ch * 8 + j][cc]);
    if (job < 2) {
      int srow = c0 * 2 + ((cc >> 4) << 5) + job * 16 + (cc & 15);
      *reinterpret_cast<us8*>(&WguT[((size_t)e * 2 * II + srow) * HH + r0 + ch * 8]) = o;
    } else {
      *reinterpret_cast<us8*>(&WdT[((size_t)e * HH + c0 + cc) * II + r0 + ch * 8]) = o;
    }
  }
}

// ---------------- router: logits, top-2, sigmoid-renorm, expert lists ----------------
__global__ __launch_bounds__(256) void k_router(const float* __restrict__ x,
                                                const float* __restrict__ Wr,
                                                const float* __restrict__ br,
                                                unsigned short* __restrict__ xb,
                                                int* __restrict__ tlist,
                                                float* __restrict__ glist,
                                                int* __restrict__ counts) {
  __shared__ float wrt[8][1024];
  __shared__ int lcount[8];
  __shared__ int lbase[8];
  __shared__ short ent_e[128];
  __shared__ short ent_slot[128];
  __shared__ float ent_g[128];
  int tid = threadIdx.x;
  for (int i = tid; i < 8192; i += 256) {
    wrt[i & 7][i >> 3] = Wr[i];
  }
  if (tid < 8) lcount[tid] = 0;
  __syncthreads();
  int w = tid >> 6, l = tid & 63;
  int t0 = blockIdx.x * 64;
  for (int it = 0; it < 16; ++it) {
    int t = t0 + w * 16 + it;
    const float4* xr = reinterpret_cast<const float4*>(x + (size_t)t * HH);
    float acc[8] = {0.f, 0.f, 0.f, 0.f, 0.f, 0.f, 0.f, 0.f};
#pragma unroll
    for (int j = 0; j < 4; ++j) {
      float4 xv = xr[j * 64 + l];
      int hbase = (j * 64 + l) * 4;
      ushort4 o;
      o.x = f2bf(xv.x); o.y = f2bf(xv.y); o.z = f2bf(xv.z); o.w = f2bf(xv.w);
      *reinterpret_cast<ushort4*>(xb + (size_t)t * HH + hbase) = o;
#pragma unroll
      for (int e = 0; e < 8; ++e) {
        float4 wv = *reinterpret_cast<const float4*>(&wrt[e][hbase]);
        acc[e] += xv.x * wv.x + xv.y * wv.y + xv.z * wv.z + xv.w * wv.w;
      }
    }
#pragma unroll
    for (int e = 0; e < 8; ++e)
#pragma unroll
      for (int off = 32; off > 0; off >>= 1) acc[e] += __shfl_xor(acc[e], off, 64);
    if (l == 0) {
      float lg[8];
#pragma unroll
      for (int e = 0; e < 8; ++e) lg[e] = acc[e] + br[e];
      int i0 = 0;
#pragma unroll
      for (int e = 1; e < 8; ++e) if (lg[e] > lg[i0]) i0 = e;
      int i1 = (i0 == 0) ? 1 : 0;
#pragma unroll
      for (int e = 0; e < 8; ++e) if (e != i0 && lg[e] > lg[i1]) i1 = e;
      float g0 = 1.f / (1.f + expf(-lg[i0]));
      float g1 = 1.f / (1.f + expf(-lg[i1]));
      float inv = 1.f / (g0 + g1 + 1e-10f);
      int idx = (w * 16 + it) * 2;
      int s0 = atomicAdd(&lcount[i0], 1);
      ent_e[idx] = (short)i0; ent_slot[idx] = (short)s0; ent_g[idx] = g0 * inv;
      int s1 = atomicAdd(&lcount[i1], 1);
      ent_e[idx + 1] = (short)i1; ent_slot[idx + 1] = (short)s1; ent_g[idx + 1] = g1 * inv;
    }
  }
  __syncthreads();
  if (tid < 8) lbase[tid] = atomicAdd(&counts[tid], lcount[tid]);
  __syncthreads();
  if (tid < 128) {
    int e = ent_e[tid];
    int slot = lbase[e] + ent_slot[tid];
    int t = t0 + (tid >> 1);
    tlist[e * TT + slot] = t;
    glist[e * TT + slot] = ent_g[tid];
  }
}

__global__ void k_offsets(const int* __restrict__ counts, int* __restrict__ offs) {
  if (threadIdx.x == 0) {
    int s = 0;
    for (int e = 0; e < EE; ++e) { offs[e] = s; s += counts[e]; }
  }
}

// ---------------- GEMM1: standard 128x128 GEMM vs interleaved WguT ----------------
// R6-proven 2-barrier structure, 4 blocks/CU. Epilogue: acc[m][n] n even =
// gate frag, n+1 = up frag of the SAME logical columns -> in-register silu.
__global__ __launch_bounds__(256, 4) void k_gemm1(
    const unsigned short* __restrict__ xb,
    const unsigned short* __restrict__ WguT,
    const int* __restrict__ tlist, const float* __restrict__ glist,
    const int* __restrict__ counts, const int* __restrict__ offs,
    unsigned short* __restrict__ hbuf) {
  __shared__ unsigned short lsA[128 * 64];
  __shared__ unsigned short lsB[128 * 64];
  __shared__ int s_tok[128];
  __shared__ float s_gate[128];

  const int e = blockIdx.z;
  const int n_e = counts[e];
  const int row0 = blockIdx.y * 128;
  if (row0 >= n_e) return;
  const int n0 = blockIdx.x * 128;   // stored-row base in WguT
  const int tid = threadIdx.x;

  if (tid < 128) {
    int r = row0 + tid;
    int tok = 0; float gt = 0.f;
    if (r < n_e) { tok = tlist[e * TT + r]; gt = glist[e * TT + r]; }
    s_tok[tid] = tok; s_gate[tid] = gt;
  }
  __syncthreads();

  const int scol = (tid & 7) ^ ((tid >> 3) & 7);
  const unsigned short* srcA[4];
  const unsigned short* srcB[4];
#pragma unroll
  for (int i = 0; i < 4; ++i) {
    int row = i * 32 + (tid >> 3);
    srcA[i] = xb + (size_t)s_tok[row] * HH + scol * 8;
    srcB[i] = WguT + ((size_t)e * 2 * II + n0 + row) * HH + scol * 8;
  }

  f32x4 zero = {0.f, 0.f, 0.f, 0.f};
  f32x4 acc[4][4];
#pragma unroll
  for (int m = 0; m < 4; ++m)
#pragma unroll
    for (int n = 0; n < 4; ++n) acc[m][n] = zero;

  const int l = tid & 63;
  const int w = tid >> 6;
  const int wr = (w >> 1) * 64;
  const int wc = (w & 1) * 64;
  const int lrow = l & 15;
  const int lk = l >> 4;
  const int swz = (l & 7) << 4;
  const int aoff0 = (wr + lrow) * 128 + lk * 16;
  const int boff0 = (wc + lrow) * 128 + lk * 16;
  const char* lcA = (const char*)lsA;
  const char* lcB = (const char*)lsB;

  for (int kt = 0; kt < HH / 64; ++kt) {
#pragma unroll
    for (int i = 0; i < 4; ++i) {
      gload_lds16(srcA[i] + kt * 64, (char*)lsA + i * 4096 + tid * 16);
      gload_lds16(srcB[i] + kt * 64, (char*)lsB + i * 4096 + tid * 16);
    }
    __syncthreads();
#pragma unroll
    for (int kk = 0; kk < 2; ++kk) {
      bf16x8 af[4], bf[4];
#pragma unroll
      for (int m = 0; m < 4; ++m)
        af[m] = *(const bf16x8*)(lcA + ((aoff0 + m * 2048 + kk * 64) ^ swz));
#pragma unroll
      for (int n = 0; n < 4; ++n)
        bf[n] = *(const bf16x8*)(lcB + ((boff0 + n * 2048 + kk * 64) ^ swz));
#pragma unroll
      for (int m = 0; m < 4; ++m)
#pragma unroll
        for (int n = 0; n < 4; ++n)
          acc[m][n] = __builtin_amdgcn_mfma_f32_16x16x32_bf16(af[m], bf[n], acc[m][n], 0, 0, 0);
    }
    __syncthreads();
  }

  const int obase = offs[e];
#pragma unroll
  for (int m = 0; m < 4; ++m)
#pragma unroll
    for (int n = 0; n < 4; n += 2)   // n = gate frag, n+1 = up frag (same cols)
#pragma unroll
      for (int r = 0; r < 4; ++r) {
        int rl = wr + m * 16 + lk * 4 + r;   // C/D: col=lane&15, row=(lane>>4)*4+reg
        if (row0 + rl < n_e) {
          float gv = acc[m][n][r];
          float uv = acc[m][n + 1][r];
          float val = gv / (1.f + __expf(-gv)) * uv * s_gate[rl];
          int L = (n0 >> 1) + (wc >> 1) + (n >> 1) * 16 + lrow;   // logical II col
          hbuf[(size_t)(obase + row0 + rl) * II + L] = f2bf(val);
        }
      }
}

// ---------------- GEMM2: out += h @ Wd (R6-proven, atomic scatter) ----------------
__global__ __launch_bounds__(256, 4) void k_gemm2(
    const unsigned short* __restrict__ hbuf,
    const unsigned short* __restrict__ WdT,   // [E][H][I] (k=I contiguous)
    const int* __restrict__ tlist,
    const int* __restrict__ counts, const int* __restrict__ offs,
    float* __restrict__ out) {
  __shared__ unsigned short lsA[128 * 64];
  __shared__ unsigned short lsB[128 * 64];
  __shared__ int s_tok[128];

  const int e = blockIdx.z;
  const int n_e = counts[e];
  const int row0 = blockIdx.y * 128;
  if (row0 >= n_e) return;
  const int n0 = blockIdx.x * 128;   // H columns
  const int tid = threadIdx.x;
  const int obase = offs[e];

  if (tid < 128) {
    int r = row0 + tid;
    s_tok[tid] = (r < n_e) ? tlist[e * TT + r] : 0;
  }
  __syncthreads();

  const int scol = (tid & 7) ^ ((tid >> 3) & 7);
  const unsigned short* srcA[4];
  const unsigned short* srcB[4];
#pragma unroll
  for (int i = 0; i < 4; ++i) {
    int row = i * 32 + (tid >> 3);
    int ar = obase + row0 + row;
    if (ar > TT * TOPK - 1) ar = TT * TOPK - 1;   // clamp pad rows inside hbuf
    srcA[i] = hbuf + (size_t)ar * II + scol * 8;
    srcB[i] = WdT + ((size_t)e * HH + n0 + row) * II + scol * 8;
  }

  f32x4 zero = {0.f, 0.f, 0.f, 0.f};
  f32x4 acc[4][4];
#pragma unroll
  for (int m = 0; m < 4; ++m)
#pragma unroll
    for (int n = 0; n < 4; ++n) acc[m][n] = zero;

  const int l = tid & 63;
  const int w = tid >> 6;
  const int wr = (w >> 1) * 64;
  const int wc = (w & 1) * 64;
  const int lrow = l & 15;
  const int lk = l >> 4;
  const int swz = (l & 7) << 4;
  const int aoff0 = (wr + lrow) * 128 + lk * 16;
  const int boff0 = (wc + lrow) * 128 + lk * 16;
  const char* lcA = (const char*)lsA;
  const char* lcB = (const char*)lsB;

  for (int kt = 0; kt < II / 64; ++kt) {
#pragma unroll
    for (int i = 0; i < 4; ++i) {
      gload_lds16(srcA[i] + kt * 64, (char*)lsA + i * 4096 + tid * 16);
      gload_lds16(srcB[i] + kt * 64, (char*)lsB + i * 4096 + tid * 16);
    }
    __syncthreads();
#pragma unroll
    for (int kk = 0; kk < 2; ++kk) {
      bf16x8 af[4], bf[4];
#pragma unroll
      for (int m = 0; m < 4; ++m)
        af[m] = *(const bf16x8*)(lcA + ((aoff0 + m * 2048 + kk * 64) ^ swz));
#pragma unroll
      for (int n = 0; n < 4; ++n)
        bf[n] = *(const bf16x8*)(lcB + ((boff0 + n * 2048 + kk * 64) ^ swz));
#pragma unroll
      for (int m = 0; m < 4; ++m)
#pragma unroll
        for (int n = 0; n < 4; ++n)
          acc[m][n] = __builtin_amdgcn_mfma_f32_16x16x32_bf16(af[m], bf[n], acc[m][n], 0, 0, 0);
    }
    __syncthreads();
  }

#pragma unroll
  for (int m = 0; m < 4; ++m)
#pragma unroll
    for (int n = 0; n < 4; ++n)
#pragma unroll
      for (int r = 0; r < 4; ++r) {
        int rl = wr + m * 16 + lk * 4 + r;
        if (row0 + rl < n_e) {
          int t = s_tok[rl];
          unsafeAtomicAdd(&out[(size_t)t * HH + n0 + wc + n * 16 + lrow], acc[m][n][r]);
        }
      }
}

extern "C" void kernel_launch(void* const* d_in, const int* in_sizes, int n_in,
                              void* d_out, int out_size, void* d_ws, size_t ws_size,
                              hipStream_t stream) {
  const float* x  = (const float*)d_in[0];
  const float* Wr = (const float*)d_in[1];
  const float* br = (const float*)d_in[2];
  const float* Wg = (const float*)d_in[3];
  const float* Wu = (const float*)d_in[4];
  const float* Wd = (const float*)d_in[5];
  float* out = (float*)d_out;

  char* ws = (char*)d_ws;
  size_t off = 0;
  auto alloc = [&](size_t bytes) {
    char* p = ws + off;
    off += (bytes + 255) & ~(size_t)255;
    return p;
  };
  unsigned short* xb   = (unsigned short*)alloc((size_t)TT * HH * 2);            // 16 MB
  unsigned short* WguT = (unsigned short*)alloc((size_t)EE * 2 * II * HH * 2);   // 64 MB
  unsigned short* WdT  = (unsigned short*)alloc((size_t)EE * HH * II * 2);       // 32 MB
  unsigned short* hbuf = (unsigned short*)alloc((size_t)TT * TOPK * II * 2);     // 64 MB
  int*   tlist  = (int*)alloc((size_t)EE * TT * 4);
  float* glist  = (float*)alloc((size_t)EE * TT * 4);
  int*   counts = (int*)alloc(128);
  int*   offs   = (int*)alloc(128);

  hipMemsetAsync(counts, 0, 128, stream);
  hipMemsetAsync(d_out, 0, (size_t)TT * HH * 4, stream);

  dim3 tall(512, 3, EE);   // fused: Wg,Wu -> WguT interleaved; Wd -> WdT
  k_transpose_all<<<tall, 256, 0, stream>>>(Wg, Wu, Wd, WguT, WdT);

  k_router<<<TT / 64, 256, 0, stream>>>(x, Wr, br, xb, tlist, glist, counts);
  k_offsets<<<1, 64, 0, stream>>>(counts, offs);

  dim3 g1(2 * II / 128, TT / 128, EE);   // 32 x 64 x 8, early-exit on empty M-tiles
  k_gemm1<<<g1, 256, 0, stream>>>(xb, WguT, tlist, glist, counts, offs, hbuf);
  dim3 g2(HH / 128, TT / 128, EE);
  k_gemm2<<<g2, 256, 0, stream>>>(hbuf, WdT, tlist, counts, offs, out);

  (void)in_sizes; (void)n_in; (void)out_size; (void)ws_size;
}